// Round 11
// baseline (377.333 us; speedup 1.0000x reference)
//
#include <hip/hip_runtime.h>
#include <hip/hip_bf16.h>

#define BATCH 4
#define SEQ   4096
#define DMODEL 1024
#define NH    16
#define DH    64
#define NCHUNK 32
#define CHUNKSZ 128
#define FEPS  1e-6f

typedef unsigned short ushort_t;
typedef __attribute__((ext_vector_type(8))) short short8;
typedef __attribute__((ext_vector_type(4))) float f32x4;
typedef __attribute__((ext_vector_type(16))) float f32x16;

__device__ __forceinline__ float bf2f(ushort_t u) {
    union { unsigned int i; float f; } x; x.i = ((unsigned int)u) << 16; return x.f;
}
__device__ __forceinline__ ushort_t f2bf(float f) {
    union { float f; unsigned int i; } x; x.f = f;
    unsigned int lsb = (x.i >> 16) & 1u;
    x.i += 0x7fffu + lsb;   // round-to-nearest-even
    return (ushort_t)(x.i >> 16);
}

__device__ __forceinline__ void load_lds16(const void* g, void* l) {
    __builtin_amdgcn_global_load_lds(
        (const __attribute__((address_space(1))) int*)g,
        (__attribute__((address_space(3))) int*)l, 16, 0, 0);
}

// ---------------------------------------------------------------------------
// x f32 -> bf16 (same layout)
// ---------------------------------------------------------------------------
__global__ __launch_bounds__(256) void cvt_k(const float* __restrict__ X,
                                             ushort_t* __restrict__ Xb, int n4)
{
    int i = blockIdx.x * blockDim.x + threadIdx.x;
    int stride = gridDim.x * blockDim.x;
    for (; i < n4; i += stride) {
        float4 v = ((const float4*)X)[i];
        ushort4 u;
        u.x = f2bf(v.x); u.y = f2bf(v.y); u.z = f2bf(v.z); u.w = f2bf(v.w);
        ((ushort4*)Xb)[i] = u;
    }
}

// ---------------------------------------------------------------------------
// All four W f32 [K,N] -> WT bf16 [N,K], one launch (blockIdx.z selects)
// ---------------------------------------------------------------------------
__global__ __launch_bounds__(256) void wt4_k(const float* __restrict__ W0,
                                             const float* __restrict__ W1,
                                             const float* __restrict__ W2,
                                             const float* __restrict__ W3,
                                             ushort_t* __restrict__ WT0)
{
    const float* Ws[4] = {W0, W1, W2, W3};
    const float* W = Ws[blockIdx.z];
    ushort_t* WT = WT0 + (size_t)blockIdx.z * DMODEL * DMODEL;
    __shared__ float tile[32][33];
    int tx = threadIdx.x & 31, ty = threadIdx.x >> 5;
    int kb = blockIdx.x << 5, nb = blockIdx.y << 5;
#pragma unroll
    for (int i = 0; i < 4; i++)
        tile[ty + i * 8][tx] = W[(size_t)(kb + ty + i * 8) * DMODEL + nb + tx];
    __syncthreads();
#pragma unroll
    for (int i = 0; i < 4; i++)
        WT[(size_t)(nb + ty + i * 8) * DMODEL + kb + tx] = f2bf(tile[tx][ty + i * 8]);
}

// ---------------------------------------------------------------------------
// MFMA GEMM, 32x32x16, 128x128 tile, 4 waves (2M x 2N), ring-3 LDS (48 KB)
// -> 3 blocks/CU (12 waves/CU): the m97/m103 occupancy regime, with the
// r8-best schedule (double-barrier phases + counted vmcnt) kept verbatim.
// Per K-tile (BK=32), phases A/B:
//   A: STAGE pair0(t+2) ; ds_read kk0 frags ; SBAR ; bar ; lgkm0 ; SBAR ;
//      prio1 ; 4 MFMA ; prio0 ; bar
//   B: STAGE pair1(t+2) ; ds_read kk1 frags ; SBAR ; bar ; lgkm0 ; SBAR ;
//      prio1 ; 4 MFMA ; prio0
//   boundary: vmcnt(4) (t+1's 4 stages landed; t+2 in flight; tail 4->0) ; bar
// WAR: reads of slot t-1 drained (lgkm0) before t-1's boundary barrier;
// stage(t+2)=slot(t-1) issues after it. RAW: vmcnt(4) before reads of t+1.
// MODE 0: fused QKV. N=3072; feature(elu+1) for n<2048; bf16 scatter [b,h,t,d].
// MODE 2: +bias, f32 row-major [M,N].
// ---------------------------------------------------------------------------
#define TBM 128
#define TBN 128
#define TBK 32

template<int MODE>
__global__ __launch_bounds__(256, 3) void mgemm32_k(const ushort_t* __restrict__ Ap,
                                                    const ushort_t* __restrict__ Bt,
                                                    const float* __restrict__ bias,
                                                    void* __restrict__ Cp,
                                                    int M, int N, int K)
{
    __shared__ short smem[24576];              // 3 x (A 4096 | B 4096) shorts = 48 KB
    const int tid = threadIdx.x;
    const int l  = tid & 63;
    const int w  = tid >> 6;                   // 0..3
    const int wm = w >> 1, wn = w & 1;         // 2 x 2 wave grid
    const int l31 = l & 31;
    const int hi  = l >> 5;                    // 0/1 -> k-group

    const size_t m0 = (size_t)blockIdx.x * TBM;
    const size_t n0 = (size_t)blockIdx.y * TBN;

    f32x16 acc[2][2];
#pragma unroll
    for (int i = 0; i < 2; i++)
#pragma unroll
        for (int j = 0; j < 2; j++)
#pragma unroll
            for (int e = 0; e < 16; e++) acc[i][j][e] = 0.f;

    // A seg sa = w*2+i: kch = sa>>1 (0..3), rb = sa&1 (row-block of 64). B same.
    auto STAGE_PAIR = [&](int slot, int k0, int i) {
        short* Asl = smem + slot * 8192;
        short* Bsl = Asl + 4096;
        const int sa  = w * 2 + i;              // 0..7 segments of 1KB
        const int kch = sa >> 1;                // k-chunk 0..3
        const int rb  = sa & 1;                 // row-block of 64
        const int ldso = (kch * 128 + rb * 64) * 8;
        load_lds16(Ap + (m0 + rb * 64 + l) * (size_t)K + k0 + kch * 8, Asl + ldso);
        load_lds16(Bt + (n0 + rb * 64 + l) * (size_t)K + k0 + kch * 8, Bsl + ldso);
    };

    const int nt = K / TBK;                     // 32 for K=1024
    STAGE_PAIR(0, 0, 0);   STAGE_PAIR(0, 0, 1);
    STAGE_PAIR(1, TBK, 0); STAGE_PAIR(1, TBK, 1);
    asm volatile("s_waitcnt vmcnt(4)" ::: "memory");   // slot0 landed; slot1 in flight
    __builtin_amdgcn_sched_barrier(0);
    __builtin_amdgcn_s_barrier();

    for (int t = 0; t < nt; ++t) {
        const short* Asl = smem + (t % 3) * 8192;
        const short* Bsl = Asl + 4096;
        const bool pre = (t + 2 < nt);
        const int pslot = (t + 2) % 3;
        const int pk0 = (t + 2) * TBK;

        // ---------------- phase A (kk=0) ----------------
        if (pre) STAGE_PAIR(pslot, pk0, 0);
        short8 a0[2], b0[2];
#pragma unroll
        for (int mt = 0; mt < 2; mt++)
            a0[mt] = *(const short8*)(Asl + (hi * 128 + wm * 64 + mt * 32 + l31) * 8);
#pragma unroll
        for (int nn = 0; nn < 2; nn++)
            b0[nn] = *(const short8*)(Bsl + (hi * 128 + wn * 64 + nn * 32 + l31) * 8);
        __builtin_amdgcn_sched_barrier(0);
        __builtin_amdgcn_s_barrier();
        asm volatile("s_waitcnt lgkmcnt(0)" ::: "memory");
        __builtin_amdgcn_sched_barrier(0);
        __builtin_amdgcn_s_setprio(1);
#pragma unroll
        for (int mt = 0; mt < 2; mt++)
#pragma unroll
            for (int nn = 0; nn < 2; nn++)
                acc[mt][nn] = __builtin_amdgcn_mfma_f32_32x32x16_bf16(
                    a0[mt], b0[nn], acc[mt][nn], 0, 0, 0);
        __builtin_amdgcn_s_setprio(0);
        __builtin_amdgcn_s_barrier();

        // ---------------- phase B (kk=1) ----------------
        if (pre) STAGE_PAIR(pslot, pk0, 1);
        short8 a1[2], b1[2];
#pragma unroll
        for (int mt = 0; mt < 2; mt++)
            a1[mt] = *(const short8*)(Asl + ((2 + hi) * 128 + wm * 64 + mt * 32 + l31) * 8);
#pragma unroll
        for (int nn = 0; nn < 2; nn++)
            b1[nn] = *(const short8*)(Bsl + ((2 + hi) * 128 + wn * 64 + nn * 32 + l31) * 8);
        __builtin_amdgcn_sched_barrier(0);
        __builtin_amdgcn_s_barrier();
        asm volatile("s_waitcnt lgkmcnt(0)" ::: "memory");
        __builtin_amdgcn_sched_barrier(0);
        __builtin_amdgcn_s_setprio(1);
#pragma unroll
        for (int mt = 0; mt < 2; mt++)
#pragma unroll
            for (int nn = 0; nn < 2; nn++)
                acc[mt][nn] = __builtin_amdgcn_mfma_f32_32x32x16_bf16(
                    a1[mt], b1[nn], acc[mt][nn], 0, 0, 0);
        __builtin_amdgcn_s_setprio(0);

        // ---------------- tile boundary ----------------
        if (t + 2 < nt) {
            asm volatile("s_waitcnt vmcnt(4)" ::: "memory");   // t+1 landed
        } else if (t + 1 < nt) {
            asm volatile("s_waitcnt vmcnt(0)" ::: "memory");   // tail drain
        }
        __builtin_amdgcn_sched_barrier(0);
        __builtin_amdgcn_s_barrier();
    }

    // epilogue: m = m0 + wm*64 + mt*32 + row ; n = n0 + wn*64 + nn*32 + l31
    // row = (reg&3) + 8*(reg>>2) + 4*hi   [m74/m101 verified C/D mapping]
#pragma unroll
    for (int mt = 0; mt < 2; mt++) {
#pragma unroll
        for (int nn = 0; nn < 2; nn++) {
#pragma unroll
            for (int reg = 0; reg < 16; reg++) {
                int row = (reg & 3) + 8 * (reg >> 2) + 4 * hi;
                int m = (int)m0 + wm * 64 + mt * 32 + row;
                int n = (int)n0 + wn * 64 + nn * 32 + l31;
                float v = acc[mt][nn][reg];
                if (MODE == 2) {
                    ((float*)Cp)[(size_t)m * N + n] = v + bias[n];
                } else {
                    if (n < 2048) v = (v > 0.f) ? (v + 1.f) : __expf(v);  // Q,K feature
                    int tns = n >> 10, nnn = n & 1023;
                    int b_ = m >> 12, t_ = m & 4095, h_ = nnn >> 6, d_ = nnn & 63;
                    ushort_t* base = (ushort_t*)Cp + (size_t)tns * BATCH * SEQ * DMODEL;
                    base[((((size_t)b_ * NH + h_) * SEQ + t_) << 6) + d_] = f2bf(v);
                }
            }
        }
    }
}

// ---------------------------------------------------------------------------
// Z[b,h,t] = 1/(sum_d Q[b,h,t,d] * cumsum_{h'<=h} K[b,h',t,d] + eps)
// 4 waves per block, one (b,t) per wave
// ---------------------------------------------------------------------------
__global__ __launch_bounds__(256) void z_k(const ushort_t* __restrict__ Q,
                                           const ushort_t* __restrict__ K,
                                           float* __restrict__ Z)
{
    int bt = blockIdx.x * 4 + (threadIdx.x >> 6);
    int b_ = bt >> 12, t_ = bt & 4095;
    int d = threadIdx.x & 63;
    float qv[NH], kv[NH];
    size_t base = (((size_t)b_ * NH) * SEQ + t_) * DH + d;
#pragma unroll
    for (int h = 0; h < NH; h++) {
        qv[h] = bf2f(Q[base + (size_t)h * SEQ * DH]);
        kv[h] = bf2f(K[base + (size_t)h * SEQ * DH]);
    }
    float ck = 0.f;
#pragma unroll
    for (int h = 0; h < NH; h++) {
        ck += kv[h];
        float p = qv[h] * ck;
#pragma unroll
        for (int off = 1; off < 64; off <<= 1) p += __shfl_xor(p, off, 64);
        if (d == 0) Z[((size_t)b_ * NH + h) * SEQ + t_] = 1.f / (p + FEPS);
    }
}

// ---------------------------------------------------------------------------
// Per-chunk S_local = K_c^T V_c  via MFMA
// ---------------------------------------------------------------------------
__global__ __launch_bounds__(256) void kv_k(const ushort_t* __restrict__ Kf,
                                            const ushort_t* __restrict__ Vf,
                                            float* __restrict__ Sloc)
{
    __shared__ short KTs[8192];
    __shared__ short VTs[8192];
    const int tid = threadIdx.x;
    const int l = tid & 63, w = tid >> 6;
    const int lr = l & 15, hi = l >> 4;
    const int blk = blockIdx.x;
    const size_t rowbase = ((size_t)(blk >> 5) * SEQ + (size_t)(blk & 31) * CHUNKSZ) * DH;
    const uint4* K16 = (const uint4*)(Kf + rowbase);
    const uint4* V16 = (const uint4*)(Vf + rowbase);
#pragma unroll
    for (int i = 0; i < 4; i++) {
        int idx = tid + i * 256;
        union { uint4 q; ushort_t us[8]; } kk, vv;
        kk.q = K16[idx]; vv.q = V16[idx];
        int j = idx >> 3, e0 = (idx & 7) << 3;
#pragma unroll
        for (int s = 0; s < 8; s++) {
            int off = ((j >> 3) * 64 + e0 + s) * 8 + (j & 7);
            KTs[off] = (short)kk.us[s];
            VTs[off] = (short)vv.us[s];
        }
    }
    __syncthreads();
    f32x4 acc[4];
#pragma unroll
    for (int nt = 0; nt < 4; nt++) acc[nt] = (f32x4){0.f, 0.f, 0.f, 0.f};
#pragma unroll
    for (int ks = 0; ks < 4; ks++) {
        short8 af = *(const short8*)(KTs + ((ks * 4 + hi) * 64 + w * 16 + lr) * 8);
        short8 bf[4];
#pragma unroll
        for (int nt = 0; nt < 4; nt++)
            bf[nt] = *(const short8*)(VTs + ((ks * 4 + hi) * 64 + nt * 16 + lr) * 8);
#pragma unroll
        for (int nt = 0; nt < 4; nt++)
            acc[nt] = __builtin_amdgcn_mfma_f32_16x16x32_bf16(af, bf[nt], acc[nt], 0, 0, 0);
    }
    float* outp = Sloc + (size_t)blk * DH * DH;
#pragma unroll
    for (int nt = 0; nt < 4; nt++)
#pragma unroll
        for (int jr = 0; jr < 4; jr++) {
            int d_ = w * 16 + hi * 4 + jr;
            int e_ = nt * 16 + lr;
            outp[d_ * DH + e_] = acc[nt][jr];
        }
}

// ---------------------------------------------------------------------------
// Exclusive prefix over chunks, element-parallel
// ---------------------------------------------------------------------------
__global__ __launch_bounds__(256) void scan_k(float* __restrict__ Sloc)
{
    int bh = blockIdx.x, seg = blockIdx.y;
    int e = seg * 256 + threadIdx.x;
    float* base = Sloc + (size_t)bh * NCHUNK * DH * DH + e;
    float acc = 0.f;
    float cur = base[0];
    for (int cc = 0; cc < NCHUNK; cc++) {
        float nxt = (cc + 1 < NCHUNK) ? base[(size_t)(cc + 1) * DH * DH] : 0.f;
        base[(size_t)cc * DH * DH] = acc;
        acc += cur;
        cur = nxt;
    }
}

// ---------------------------------------------------------------------------
// MFMA attention chunk kernel (validated round 3)
// ---------------------------------------------------------------------------
__global__ __launch_bounds__(256) void attn_k(const ushort_t* __restrict__ Qf,
                                              const ushort_t* __restrict__ Kf,
                                              const ushort_t* __restrict__ Vf,
                                              const float* __restrict__ Sloc,
                                              const float* __restrict__ Z,
                                              ushort_t* __restrict__ A)
{
    __shared__ short smem[36864];
    short* Qs  = smem;
    short* Ks  = smem + 8192;
    short* Ps  = smem + 8192;
    short* VTs = smem + 24576;
    short* STs = smem + 32768;

    const int tid = threadIdx.x;
    const int l = tid & 63, w = tid >> 6;
    const int lr = l & 15, hi = l >> 4;
    const int blk = blockIdx.x;
    const int c = blk & (NCHUNK - 1), bh = blk >> 5;
    const int b_ = bh >> 4, h_ = bh & 15;
    const size_t rowbase = ((size_t)bh * SEQ + (size_t)c * CHUNKSZ) * DH;

#pragma unroll
    for (int ii = 0; ii < 4; ii++) {
        int s = w * 4 + ii;
        int kc2 = s >> 1, rh = (s & 1) << 6;
        int ldso = (kc2 * 128 + rh) * 8;
        load_lds16(Qf + rowbase + (size_t)(rh + l) * DH + kc2 * 8, Qs + ldso);
        load_lds16(Kf + rowbase + (size_t)(rh + l) * DH + kc2 * 8, Ks + ldso);
    }
    {
        const uint4* V16 = (const uint4*)(Vf + rowbase);
#pragma unroll
        for (int i = 0; i < 4; i++) {
            int idx = tid + i * 256;
            union { uint4 q; ushort_t us[8]; } vv;
            vv.q = V16[idx];
            int j = idx >> 3, e0 = (idx & 7) << 3;
#pragma unroll
            for (int s = 0; s < 8; s++)
                VTs[((j >> 3) * 64 + e0 + s) * 8 + (j & 7)] = (short)vv.us[s];
        }
    }
    {
        const float4* S16 = (const float4*)(Sloc + (size_t)blk * DH * DH);
#pragma unroll
        for (int i = 0; i < 4; i++) {
            int idx = tid + i * 256;
            float4 f = S16[idx];
            int d = idx >> 4, e0 = (idx & 15) << 2;
            STs[((d >> 3) * 64 + e0 + 0) * 8 + (d & 7)] = (short)f2bf(f.x);
            STs[((d >> 3) * 64 + e0 + 1) * 8 + (d & 7)] = (short)f2bf(f.y);
            STs[((d >> 3) * 64 + e0 + 2) * 8 + (d & 7)] = (short)f2bf(f.z);
            STs[((d >> 3) * 64 + e0 + 3) * 8 + (d & 7)] = (short)f2bf(f.w);
        }
    }
    __syncthreads();

    f32x4 acc1[2][8];
#pragma unroll
    for (int mt = 0; mt < 2; mt++)
#pragma unroll
        for (int nt = 0; nt < 8; nt++) acc1[mt][nt] = (f32x4){0.f, 0.f, 0.f, 0.f};
#pragma unroll
    for (int ks = 0; ks < 2; ks++) {
        short8 af[2], bf[8];
#pragma unroll
        for (int mt = 0; mt < 2; mt++)
            af[mt] = *(const short8*)(Qs + ((ks * 4 + hi) * 128 + w * 32 + mt * 16 + lr) * 8);
#pragma unroll
        for (int nt = 0; nt < 8; nt++)
            bf[nt] = *(const short8*)(Ks + ((ks * 4 + hi) * 128 + nt * 16 + lr) * 8);
#pragma unroll
        for (int mt = 0; mt < 2; mt++)
#pragma unroll
            for (int nt = 0; nt < 8; nt++)
                acc1[mt][nt] = __builtin_amdgcn_mfma_f32_16x16x32_bf16(
                    af[mt], bf[nt], acc1[mt][nt], 0, 0, 0);
    }
    __syncthreads();

#pragma unroll
    for (int mt = 0; mt < 2; mt++)
#pragma unroll
        for (int nt = 0; nt < 8; nt++)
#pragma unroll
            for (int jr = 0; jr < 4; jr++) {
                int i_ = w * 32 + mt * 16 + hi * 4 + jr;
                int j_ = nt * 16 + lr;
                float v = (j_ <= i_) ? acc1[mt][nt][jr] : 0.f;
                Ps[((j_ >> 3) * 128 + i_) * 8 + (j_ & 7)] = (short)f2bf(v);
            }
    __syncthreads();

    f32x4 acc2[2][4];
#pragma unroll
    for (int mt = 0; mt < 2; mt++)
#pragma unroll
        for (int nt = 0; nt < 4; nt++) acc2[mt][nt] = (f32x4){0.f, 0.f, 0.f, 0.f};
#pragma unroll
    for (int ks = 0; ks < 4; ks++) {
        short8 af[2], bf[4];
#pragma unroll
        for (int mt = 0; mt < 2; mt++)
            af[mt] = *(const short8*)(Ps + ((ks * 4 + hi) * 128 + w * 32 + mt * 16 + lr) * 8);
#pragma unroll
        for (int nt = 0; nt < 4; nt++)
            bf[nt] = *(const short8*)(VTs + ((ks * 4 + hi) * 64 + nt * 16 + lr) * 8);
#pragma unroll
        for (int mt = 0; mt < 2; mt++)
#pragma unroll
            for (int nt = 0; nt < 4; nt++)
                acc2[mt][nt] = __builtin_amdgcn_mfma_f32_16x16x32_bf16(
                    af[mt], bf[nt], acc2[mt][nt], 0, 0, 0);
    }
#pragma unroll
    for (int ks = 0; ks < 2; ks++) {
        short8 af[2], bf[4];
#pragma unroll
        for (int mt = 0; mt < 2; mt++)
            af[mt] = *(const short8*)(Qs + ((ks * 4 + hi) * 128 + w * 32 + mt * 16 + lr) * 8);
#pragma unroll
        for (int nt = 0; nt < 4; nt++)
            bf[nt] = *(const short8*)(STs + ((ks * 4 + hi) * 64 + nt * 16 + lr) * 8);
#pragma unroll
        for (int mt = 0; mt < 2; mt++)
#pragma unroll
            for (int nt = 0; nt < 4; nt++)
                acc2[mt][nt] = __builtin_amdgcn_mfma_f32_16x16x32_bf16(
                    af[mt], bf[nt], acc2[mt][nt], 0, 0, 0);
    }

#pragma unroll
    for (int mt = 0; mt < 2; mt++) {
#pragma unroll
        for (int jr = 0; jr < 4; jr++) {
            int i_ = w * 32 + mt * 16 + hi * 4 + jr;
            int t_ = c * CHUNKSZ + i_;
            float z = Z[(size_t)bh * SEQ + t_];
            ushort_t* op = A + (((size_t)(b_ * SEQ + t_)) * NH + h_) * DH;
#pragma unroll
            for (int nt = 0; nt < 4; nt++)
                op[nt * 16 + lr] = f2bf(acc2[mt][nt][jr] * z);
        }
    }
}

// ---------------------------------------------------------------------------
extern "C" void kernel_launch(void* const* d_in, const int* in_sizes, int n_in,
                              void* d_out, int out_size, void* d_ws, size_t ws_size,
                              hipStream_t stream)
{
    const float* x  = (const float*)d_in[0];
    const float* Wq = (const float*)d_in[1];
    const float* Wk = (const float*)d_in[2];
    const float* Wv = (const float*)d_in[3];
    const float* Wo = (const float*)d_in[4];
    const float* bo = (const float*)d_in[5];
    float* out = (float*)d_out;

    const size_t NEL = (size_t)BATCH * SEQ * DMODEL;
    const size_t WEL = (size_t)DMODEL * DMODEL;
    ushort_t* Qb  = (ushort_t*)d_ws;                   // Q,K,V contiguous (fused scatter)
    ushort_t* Kb  = Qb + NEL;
    ushort_t* Vb  = Kb + NEL;
    ushort_t* XAb = Vb + NEL;                          // x bf16, later attn out
    float*    Zb  = (float*)(XAb + NEL);
    ushort_t* WTq = (ushort_t*)(Zb + (size_t)BATCH * NH * SEQ);  // WTq|WTk|WTv|WTo contiguous
    ushort_t* WTo = WTq + 3 * WEL;
    float*    Sl  = (float*)d_out;                     // scratch; final gemm overwrites

    const int M = BATCH * SEQ;

    cvt_k<<<dim3(2048), dim3(256), 0, stream>>>(x, XAb, (int)(NEL / 4));
    wt4_k<<<dim3(32, 32, 4), dim3(256), 0, stream>>>(Wq, Wk, Wv, Wo, WTq);

    // fused QKV: N = 3072 over concatenated [WTq|WTk|WTv]
    mgemm32_k<0><<<dim3(M / TBM, 3 * DMODEL / TBN), dim3(256), 0, stream>>>(
        XAb, WTq, nullptr, Qb, M, 3 * DMODEL, DMODEL);

    z_k<<<dim3(BATCH * SEQ / 4), dim3(256), 0, stream>>>(Qb, Kb, Zb);

    kv_k<<<dim3(BATCH * NH * NCHUNK), dim3(256), 0, stream>>>(Kb, Vb, Sl);
    scan_k<<<dim3(BATCH * NH, 16), dim3(256), 0, stream>>>(Sl);
    attn_k<<<dim3(BATCH * NH * NCHUNK), dim3(256), 0, stream>>>(Qb, Kb, Vb, Sl, Zb, XAb);

    mgemm32_k<2><<<dim3(M / TBM, DMODEL / TBN), dim3(256), 0, stream>>>(
        XAb, WTo, bo, out, M, DMODEL, DMODEL);
}

// Round 12
// 287.924 us; speedup vs baseline: 1.3105x; 1.3105x over previous
//
#include <hip/hip_runtime.h>
#include <hip/hip_bf16.h>

#define BATCH 4
#define SEQ   4096
#define DMODEL 1024
#define NH    16
#define DH    64
#define NCHUNK 32
#define CHUNKSZ 128
#define FEPS  1e-6f

typedef unsigned short ushort_t;
typedef __attribute__((ext_vector_type(8))) short short8;
typedef __attribute__((ext_vector_type(4))) float f32x4;
typedef __attribute__((ext_vector_type(16))) float f32x16;

__device__ __forceinline__ float bf2f(ushort_t u) {
    union { unsigned int i; float f; } x; x.i = ((unsigned int)u) << 16; return x.f;
}
__device__ __forceinline__ ushort_t f2bf(float f) {
    union { float f; unsigned int i; } x; x.f = f;
    unsigned int lsb = (x.i >> 16) & 1u;
    x.i += 0x7fffu + lsb;   // round-to-nearest-even
    return (ushort_t)(x.i >> 16);
}

__device__ __forceinline__ void load_lds16(const void* g, void* l) {
    __builtin_amdgcn_global_load_lds(
        (const __attribute__((address_space(1))) int*)g,
        (__attribute__((address_space(3))) int*)l, 16, 0, 0);
}

// ---------------------------------------------------------------------------
// x f32 -> bf16 (same layout)
// ---------------------------------------------------------------------------
__global__ __launch_bounds__(256) void cvt_k(const float* __restrict__ X,
                                             ushort_t* __restrict__ Xb, int n4)
{
    int i = blockIdx.x * blockDim.x + threadIdx.x;
    int stride = gridDim.x * blockDim.x;
    for (; i < n4; i += stride) {
        float4 v = ((const float4*)X)[i];
        ushort4 u;
        u.x = f2bf(v.x); u.y = f2bf(v.y); u.z = f2bf(v.z); u.w = f2bf(v.w);
        ((ushort4*)Xb)[i] = u;
    }
}

// ---------------------------------------------------------------------------
// All four W f32 [K,N] -> WT bf16 [N,K], one launch (blockIdx.z selects)
// ---------------------------------------------------------------------------
__global__ __launch_bounds__(256) void wt4_k(const float* __restrict__ W0,
                                             const float* __restrict__ W1,
                                             const float* __restrict__ W2,
                                             const float* __restrict__ W3,
                                             ushort_t* __restrict__ WT0)
{
    const float* Ws[4] = {W0, W1, W2, W3};
    const float* W = Ws[blockIdx.z];
    ushort_t* WT = WT0 + (size_t)blockIdx.z * DMODEL * DMODEL;
    __shared__ float tile[32][33];
    int tx = threadIdx.x & 31, ty = threadIdx.x >> 5;
    int kb = blockIdx.x << 5, nb = blockIdx.y << 5;
#pragma unroll
    for (int i = 0; i < 4; i++)
        tile[ty + i * 8][tx] = W[(size_t)(kb + ty + i * 8) * DMODEL + nb + tx];
    __syncthreads();
#pragma unroll
    for (int i = 0; i < 4; i++)
        WT[(size_t)(nb + ty + i * 8) * DMODEL + kb + tx] = f2bf(tile[tx][ty + i * 8]);
}

// ---------------------------------------------------------------------------
// MFMA GEMM, 32x32x16, 4-slot ring + counted vmcnt + per-phase double barriers
// (r8 configuration verbatim — confirmed best of 7 variants: 144 us QKV).
// 256x256 tile, BK=32, 8 waves (2M x 4N), 2-D grid.
// MODE 0: fused QKV. N=3072; feature(elu+1) for n<2048; bf16 scatter [b,h,t,d].
// MODE 2: +bias, f32 row-major [M,N].
// ---------------------------------------------------------------------------
#define TBM 256
#define TBN 256
#define TBK 32

template<int MODE>
__global__ __launch_bounds__(512, 2) void mgemm32_k(const ushort_t* __restrict__ Ap,
                                                    const ushort_t* __restrict__ Bt,
                                                    const float* __restrict__ bias,
                                                    void* __restrict__ Cp,
                                                    int M, int N, int K)
{
    __shared__ short smem[65536];              // 4 x (A 8192 | B 8192) shorts
    const int tid = threadIdx.x;
    const int l  = tid & 63;
    const int w  = tid >> 6;
    const int wm = w >> 2, wn = w & 3;         // 2 x 4 wave grid
    const int l31 = l & 31;
    const int hi  = l >> 5;                    // 0/1 -> k-group

    const size_t m0 = (size_t)blockIdx.x * TBM;
    const size_t n0 = (size_t)blockIdx.y * TBN;

    f32x16 acc[4][2];
#pragma unroll
    for (int i = 0; i < 4; i++)
#pragma unroll
        for (int j = 0; j < 2; j++)
#pragma unroll
            for (int e = 0; e < 16; e++) acc[i][j][e] = 0.f;

    auto STAGE_PAIR = [&](int slot, int k0, int i) {
        short* Asl = smem + slot * 16384;
        short* Bsl = Asl + 8192;
        const int sa  = w * 2 + i;              // 0..15 segments of 1KB
        const int kch = sa >> 2;                // k-chunk 0..3
        const int rb  = sa & 3;                 // row-block of 64
        const int ldso = (kch * 256 + rb * 64) * 8;
        load_lds16(Ap + (m0 + rb * 64 + l) * (size_t)K + k0 + kch * 8, Asl + ldso);
        load_lds16(Bt + (n0 + rb * 64 + l) * (size_t)K + k0 + kch * 8, Bsl + ldso);
    };

    const int nt = K / TBK;                     // 32 for K=1024
    STAGE_PAIR(0, 0, 0);       STAGE_PAIR(0, 0, 1);
    STAGE_PAIR(1, TBK, 0);     STAGE_PAIR(1, TBK, 1);
    STAGE_PAIR(2, 2 * TBK, 0); STAGE_PAIR(2, 2 * TBK, 1);
    asm volatile("s_waitcnt vmcnt(8)" ::: "memory");   // tile0 landed; 1,2 in flight
    __builtin_amdgcn_sched_barrier(0);
    __builtin_amdgcn_s_barrier();

    for (int t = 0; t < nt; ++t) {
        const short* Asl = smem + (t & 3) * 16384;
        const short* Bsl = Asl + 8192;
        const bool pre = (t + 3 < nt);
        const int pslot = (t + 3) & 3;
        const int pk0 = (t + 3) * TBK;

        // ---------------- phase A (kk=0) ----------------
        if (pre) STAGE_PAIR(pslot, pk0, 0);
        short8 a0[4], b0[2];
#pragma unroll
        for (int mt = 0; mt < 4; mt++)
            a0[mt] = *(const short8*)(Asl + (hi * 256 + wm * 128 + mt * 32 + l31) * 8);
#pragma unroll
        for (int nn = 0; nn < 2; nn++)
            b0[nn] = *(const short8*)(Bsl + (hi * 256 + wn * 64 + nn * 32 + l31) * 8);
        __builtin_amdgcn_sched_barrier(0);
        __builtin_amdgcn_s_barrier();
        asm volatile("s_waitcnt lgkmcnt(0)" ::: "memory");
        __builtin_amdgcn_sched_barrier(0);
        __builtin_amdgcn_s_setprio(1);
#pragma unroll
        for (int mt = 0; mt < 4; mt++)
#pragma unroll
            for (int nn = 0; nn < 2; nn++)
                acc[mt][nn] = __builtin_amdgcn_mfma_f32_32x32x16_bf16(
                    a0[mt], b0[nn], acc[mt][nn], 0, 0, 0);
        __builtin_amdgcn_s_setprio(0);
        __builtin_amdgcn_s_barrier();

        // ---------------- phase B (kk=1) ----------------
        if (pre) STAGE_PAIR(pslot, pk0, 1);
        short8 a1[4], b1[2];
#pragma unroll
        for (int mt = 0; mt < 4; mt++)
            a1[mt] = *(const short8*)(Asl + ((2 + hi) * 256 + wm * 128 + mt * 32 + l31) * 8);
#pragma unroll
        for (int nn = 0; nn < 2; nn++)
            b1[nn] = *(const short8*)(Bsl + ((2 + hi) * 256 + wn * 64 + nn * 32 + l31) * 8);
        __builtin_amdgcn_sched_barrier(0);
        __builtin_amdgcn_s_barrier();
        asm volatile("s_waitcnt lgkmcnt(0)" ::: "memory");
        __builtin_amdgcn_sched_barrier(0);
        __builtin_amdgcn_s_setprio(1);
#pragma unroll
        for (int mt = 0; mt < 4; mt++)
#pragma unroll
            for (int nn = 0; nn < 2; nn++)
                acc[mt][nn] = __builtin_amdgcn_mfma_f32_32x32x16_bf16(
                    a1[mt], b1[nn], acc[mt][nn], 0, 0, 0);
        __builtin_amdgcn_s_setprio(0);

        // ---------------- tile boundary ----------------
        if (t + 3 < nt) {
            asm volatile("s_waitcnt vmcnt(8)" ::: "memory");   // t+1 landed
        } else if (t + 2 < nt) {
            asm volatile("s_waitcnt vmcnt(4)" ::: "memory");
        } else if (t + 1 < nt) {
            asm volatile("s_waitcnt vmcnt(0)" ::: "memory");
        }
        __builtin_amdgcn_sched_barrier(0);
        __builtin_amdgcn_s_barrier();
    }

    // epilogue: m = m0+wm*128+mt*32+row, n = n0+wn*64+nn*32+col
    // col = l&31, row = (reg&3) + 8*(reg>>2) + 4*(l>>5)
#pragma unroll
    for (int mt = 0; mt < 4; mt++) {
#pragma unroll
        for (int nn = 0; nn < 2; nn++) {
#pragma unroll
            for (int reg = 0; reg < 16; reg++) {
                int row = (reg & 3) + 8 * (reg >> 2) + 4 * hi;
                int m = (int)m0 + wm * 128 + mt * 32 + row;
                int n = (int)n0 + wn * 64 + nn * 32 + l31;
                float v = acc[mt][nn][reg];
                if (MODE == 2) {
                    ((float*)Cp)[(size_t)m * N + n] = v + bias[n];
                } else {
                    if (n < 2048) v = (v > 0.f) ? (v + 1.f) : __expf(v);  // Q,K feature
                    int tns = n >> 10, nnn = n & 1023;
                    int b_ = m >> 12, t_ = m & 4095, h_ = nnn >> 6, d_ = nnn & 63;
                    ushort_t* base = (ushort_t*)Cp + (size_t)tns * BATCH * SEQ * DMODEL;
                    base[((((size_t)b_ * NH + h_) * SEQ + t_) << 6) + d_] = f2bf(v);
                }
            }
        }
    }
}

// ---------------------------------------------------------------------------
// Z[b,h,t] = 1/(sum_d Q[b,h,t,d] * cumsum_{h'<=h} K[b,h',t,d] + eps)
// ---------------------------------------------------------------------------
__global__ __launch_bounds__(256) void z_k(const ushort_t* __restrict__ Q,
                                           const ushort_t* __restrict__ K,
                                           float* __restrict__ Z)
{
    int bt = blockIdx.x * 4 + (threadIdx.x >> 6);
    int b_ = bt >> 12, t_ = bt & 4095;
    int d = threadIdx.x & 63;
    float qv[NH], kv[NH];
    size_t base = (((size_t)b_ * NH) * SEQ + t_) * DH + d;
#pragma unroll
    for (int h = 0; h < NH; h++) {
        qv[h] = bf2f(Q[base + (size_t)h * SEQ * DH]);
        kv[h] = bf2f(K[base + (size_t)h * SEQ * DH]);
    }
    float ck = 0.f;
#pragma unroll
    for (int h = 0; h < NH; h++) {
        ck += kv[h];
        float p = qv[h] * ck;
#pragma unroll
        for (int off = 1; off < 64; off <<= 1) p += __shfl_xor(p, off, 64);
        if (d == 0) Z[((size_t)b_ * NH + h) * SEQ + t_] = 1.f / (p + FEPS);
    }
}

// ---------------------------------------------------------------------------
// Per-chunk S_local = K_c^T V_c  via MFMA; output bf16 (halves S traffic)
// ---------------------------------------------------------------------------
__global__ __launch_bounds__(256) void kv_k(const ushort_t* __restrict__ Kf,
                                            const ushort_t* __restrict__ Vf,
                                            ushort_t* __restrict__ Sloc)
{
    __shared__ short KTs[8192];
    __shared__ short VTs[8192];
    const int tid = threadIdx.x;
    const int l = tid & 63, w = tid >> 6;
    const int lr = l & 15, hi = l >> 4;
    const int blk = blockIdx.x;
    const size_t rowbase = ((size_t)(blk >> 5) * SEQ + (size_t)(blk & 31) * CHUNKSZ) * DH;
    const uint4* K16 = (const uint4*)(Kf + rowbase);
    const uint4* V16 = (const uint4*)(Vf + rowbase);
#pragma unroll
    for (int i = 0; i < 4; i++) {
        int idx = tid + i * 256;
        union { uint4 q; ushort_t us[8]; } kk, vv;
        kk.q = K16[idx]; vv.q = V16[idx];
        int j = idx >> 3, e0 = (idx & 7) << 3;
#pragma unroll
        for (int s = 0; s < 8; s++) {
            int off = ((j >> 3) * 64 + e0 + s) * 8 + (j & 7);
            KTs[off] = (short)kk.us[s];
            VTs[off] = (short)vv.us[s];
        }
    }
    __syncthreads();
    f32x4 acc[4];
#pragma unroll
    for (int nt = 0; nt < 4; nt++) acc[nt] = (f32x4){0.f, 0.f, 0.f, 0.f};
#pragma unroll
    for (int ks = 0; ks < 4; ks++) {
        short8 af = *(const short8*)(KTs + ((ks * 4 + hi) * 64 + w * 16 + lr) * 8);
        short8 bf[4];
#pragma unroll
        for (int nt = 0; nt < 4; nt++)
            bf[nt] = *(const short8*)(VTs + ((ks * 4 + hi) * 64 + nt * 16 + lr) * 8);
#pragma unroll
        for (int nt = 0; nt < 4; nt++)
            acc[nt] = __builtin_amdgcn_mfma_f32_16x16x32_bf16(af, bf[nt], acc[nt], 0, 0, 0);
    }
    ushort_t* outp = Sloc + (size_t)blk * DH * DH;
#pragma unroll
    for (int nt = 0; nt < 4; nt++)
#pragma unroll
        for (int jr = 0; jr < 4; jr++) {
            int d_ = w * 16 + hi * 4 + jr;
            int e_ = nt * 16 + lr;
            outp[d_ * DH + e_] = f2bf(acc[nt][jr]);
        }
}

// ---------------------------------------------------------------------------
// Exclusive prefix over chunks, element-parallel; bf16 in/out, f32 accum
// ---------------------------------------------------------------------------
__global__ __launch_bounds__(256) void scan_k(ushort_t* __restrict__ Sloc)
{
    int bh = blockIdx.x, seg = blockIdx.y;
    int e = seg * 256 + threadIdx.x;
    ushort_t* base = Sloc + (size_t)bh * NCHUNK * DH * DH + e;
    float acc = 0.f;
    float cur = bf2f(base[0]);
    for (int cc = 0; cc < NCHUNK; cc++) {
        float nxt = (cc + 1 < NCHUNK) ? bf2f(base[(size_t)(cc + 1) * DH * DH]) : 0.f;
        base[(size_t)cc * DH * DH] = f2bf(acc);
        acc += cur;
        cur = nxt;
    }
}

// ---------------------------------------------------------------------------
// MFMA attention chunk kernel; S_pre now bf16 (direct-copy staging)
// ---------------------------------------------------------------------------
__global__ __launch_bounds__(256) void attn_k(const ushort_t* __restrict__ Qf,
                                              const ushort_t* __restrict__ Kf,
                                              const ushort_t* __restrict__ Vf,
                                              const ushort_t* __restrict__ Sloc,
                                              const float* __restrict__ Z,
                                              ushort_t* __restrict__ A)
{
    __shared__ short smem[36864];
    short* Qs  = smem;
    short* Ks  = smem + 8192;
    short* Ps  = smem + 8192;
    short* VTs = smem + 24576;
    short* STs = smem + 32768;

    const int tid = threadIdx.x;
    const int l = tid & 63, w = tid >> 6;
    const int lr = l & 15, hi = l >> 4;
    const int blk = blockIdx.x;
    const int c = blk & (NCHUNK - 1), bh = blk >> 5;
    const int b_ = bh >> 4, h_ = bh & 15;
    const size_t rowbase = ((size_t)bh * SEQ + (size_t)c * CHUNKSZ) * DH;

#pragma unroll
    for (int ii = 0; ii < 4; ii++) {
        int s = w * 4 + ii;
        int kc2 = s >> 1, rh = (s & 1) << 6;
        int ldso = (kc2 * 128 + rh) * 8;
        load_lds16(Qf + rowbase + (size_t)(rh + l) * DH + kc2 * 8, Qs + ldso);
        load_lds16(Kf + rowbase + (size_t)(rh + l) * DH + kc2 * 8, Ks + ldso);
    }
    {
        const uint4* V16 = (const uint4*)(Vf + rowbase);
#pragma unroll
        for (int i = 0; i < 4; i++) {
            int idx = tid + i * 256;
            union { uint4 q; ushort_t us[8]; } vv;
            vv.q = V16[idx];
            int j = idx >> 3, e0 = (idx & 7) << 3;
#pragma unroll
            for (int s = 0; s < 8; s++)
                VTs[((j >> 3) * 64 + e0 + s) * 8 + (j & 7)] = (short)vv.us[s];
        }
    }
    {
        const uint4* S16 = (const uint4*)(Sloc + (size_t)blk * DH * DH);
#pragma unroll
        for (int i = 0; i < 2; i++) {
            int idx = tid + i * 256;              // 512 x 16B = 64x64 bf16
            union { uint4 q; ushort_t us[8]; } ss;
            ss.q = S16[idx];
            int d = idx >> 3, e0 = (idx & 7) << 3;
#pragma unroll
            for (int s = 0; s < 8; s++)
                STs[((d >> 3) * 64 + e0 + s) * 8 + (d & 7)] = (short)ss.us[s];
        }
    }
    __syncthreads();

    f32x4 acc1[2][8];
#pragma unroll
    for (int mt = 0; mt < 2; mt++)
#pragma unroll
        for (int nt = 0; nt < 8; nt++) acc1[mt][nt] = (f32x4){0.f, 0.f, 0.f, 0.f};
#pragma unroll
    for (int ks = 0; ks < 2; ks++) {
        short8 af[2], bf[8];
#pragma unroll
        for (int mt = 0; mt < 2; mt++)
            af[mt] = *(const short8*)(Qs + ((ks * 4 + hi) * 128 + w * 32 + mt * 16 + lr) * 8);
#pragma unroll
        for (int nt = 0; nt < 8; nt++)
            bf[nt] = *(const short8*)(Ks + ((ks * 4 + hi) * 128 + nt * 16 + lr) * 8);
#pragma unroll
        for (int mt = 0; mt < 2; mt++)
#pragma unroll
            for (int nt = 0; nt < 8; nt++)
                acc1[mt][nt] = __builtin_amdgcn_mfma_f32_16x16x32_bf16(
                    af[mt], bf[nt], acc1[mt][nt], 0, 0, 0);
    }
    __syncthreads();

#pragma unroll
    for (int mt = 0; mt < 2; mt++)
#pragma unroll
        for (int nt = 0; nt < 8; nt++)
#pragma unroll
            for (int jr = 0; jr < 4; jr++) {
                int i_ = w * 32 + mt * 16 + hi * 4 + jr;
                int j_ = nt * 16 + lr;
                float v = (j_ <= i_) ? acc1[mt][nt][jr] : 0.f;
                Ps[((j_ >> 3) * 128 + i_) * 8 + (j_ & 7)] = (short)f2bf(v);
            }
    __syncthreads();

    f32x4 acc2[2][4];
#pragma unroll
    for (int mt = 0; mt < 2; mt++)
#pragma unroll
        for (int nt = 0; nt < 4; nt++) acc2[mt][nt] = (f32x4){0.f, 0.f, 0.f, 0.f};
#pragma unroll
    for (int ks = 0; ks < 4; ks++) {
        short8 af[2], bf[4];
#pragma unroll
        for (int mt = 0; mt < 2; mt++)
            af[mt] = *(const short8*)(Ps + ((ks * 4 + hi) * 128 + w * 32 + mt * 16 + lr) * 8);
#pragma unroll
        for (int nt = 0; nt < 4; nt++)
            bf[nt] = *(const short8*)(VTs + ((ks * 4 + hi) * 64 + nt * 16 + lr) * 8);
#pragma unroll
        for (int mt = 0; mt < 2; mt++)
#pragma unroll
            for (int nt = 0; nt < 4; nt++)
                acc2[mt][nt] = __builtin_amdgcn_mfma_f32_16x16x32_bf16(
                    af[mt], bf[nt], acc2[mt][nt], 0, 0, 0);
    }
#pragma unroll
    for (int ks = 0; ks < 2; ks++) {
        short8 af[2], bf[4];
#pragma unroll
        for (int mt = 0; mt < 2; mt++)
            af[mt] = *(const short8*)(Qs + ((ks * 4 + hi) * 128 + w * 32 + mt * 16 + lr) * 8);
#pragma unroll
        for (int nt = 0; nt < 4; nt++)
            bf[nt] = *(const short8*)(STs + ((ks * 4 + hi) * 64 + nt * 16 + lr) * 8);
#pragma unroll
        for (int mt = 0; mt < 2; mt++)
#pragma unroll
            for (int nt = 0; nt < 4; nt++)
                acc2[mt][nt] = __builtin_amdgcn_mfma_f32_16x16x32_bf16(
                    af[mt], bf[nt], acc2[mt][nt], 0, 0, 0);
    }

#pragma unroll
    for (int mt = 0; mt < 2; mt++) {
#pragma unroll
        for (int jr = 0; jr < 4; jr++) {
            int i_ = w * 32 + mt * 16 + hi * 4 + jr;
            int t_ = c * CHUNKSZ + i_;
            float z = Z[(size_t)bh * SEQ + t_];
            ushort_t* op = A + (((size_t)(b_ * SEQ + t_)) * NH + h_) * DH;
#pragma unroll
            for (int nt = 0; nt < 4; nt++)
                op[nt * 16 + lr] = f2bf(acc2[mt][nt][jr] * z);
        }
    }
}

// ---------------------------------------------------------------------------
extern "C" void kernel_launch(void* const* d_in, const int* in_sizes, int n_in,
                              void* d_out, int out_size, void* d_ws, size_t ws_size,
                              hipStream_t stream)
{
    const float* x  = (const float*)d_in[0];
    const float* Wq = (const float*)d_in[1];
    const float* Wk = (const float*)d_in[2];
    const float* Wv = (const float*)d_in[3];
    const float* Wo = (const float*)d_in[4];
    const float* bo = (const float*)d_in[5];
    float* out = (float*)d_out;

    const size_t NEL = (size_t)BATCH * SEQ * DMODEL;
    const size_t WEL = (size_t)DMODEL * DMODEL;
    ushort_t* Qb  = (ushort_t*)d_ws;                   // Q,K,V contiguous (fused scatter)
    ushort_t* Kb  = Qb + NEL;
    ushort_t* Vb  = Kb + NEL;
    ushort_t* XAb = Vb + NEL;                          // x bf16, later attn out
    float*    Zb  = (float*)(XAb + NEL);
    ushort_t* WTq = (ushort_t*)(Zb + (size_t)BATCH * NH * SEQ);  // WTq|WTk|WTv|WTo contiguous
    ushort_t* WTo = WTq + 3 * WEL;
    ushort_t* Sl  = (ushort_t*)d_out;                  // bf16 scratch; final gemm overwrites

    const int M = BATCH * SEQ;

    cvt_k<<<dim3(2048), dim3(256), 0, stream>>>(x, XAb, (int)(NEL / 4));
    wt4_k<<<dim3(32, 32, 4), dim3(256), 0, stream>>>(Wq, Wk, Wv, Wo, WTq);

    // fused QKV: N = 3072 over concatenated [WTq|WTk|WTv]; 2-D grid (r8 locality)
    mgemm32_k<0><<<dim3(M / TBM, 3 * DMODEL / TBN), dim3(512), 0, stream>>>(
        XAb, WTq, nullptr, Qb, M, 3 * DMODEL, DMODEL);

    z_k<<<dim3(BATCH * SEQ / 4), dim3(256), 0, stream>>>(Qb, Kb, Zb);

    kv_k<<<dim3(BATCH * NH * NCHUNK), dim3(256), 0, stream>>>(Kb, Vb, Sl);
    scan_k<<<dim3(BATCH * NH, 16), dim3(256), 0, stream>>>(Sl);
    attn_k<<<dim3(BATCH * NH * NCHUNK), dim3(256), 0, stream>>>(Qb, Kb, Vb, Sl, Zb, XAb);

    mgemm32_k<2><<<dim3(M / TBM, DMODEL / TBN), dim3(512), 0, stream>>>(
        XAb, WTo, bo, out, M, DMODEL, DMODEL);
}

// Round 13
// 284.885 us; speedup vs baseline: 1.3245x; 1.0107x over previous
//
#include <hip/hip_runtime.h>
#include <hip/hip_bf16.h>

#define BATCH 4
#define SEQ   4096
#define DMODEL 1024
#define NH    16
#define DH    64
#define NCHUNK 32
#define CHUNKSZ 128
#define FEPS  1e-6f

typedef unsigned short ushort_t;
typedef __attribute__((ext_vector_type(8))) short short8;
typedef __attribute__((ext_vector_type(4))) float f32x4;
typedef __attribute__((ext_vector_type(16))) float f32x16;

__device__ __forceinline__ float bf2f(ushort_t u) {
    union { unsigned int i; float f; } x; x.i = ((unsigned int)u) << 16; return x.f;
}
__device__ __forceinline__ ushort_t f2bf(float f) {
    union { float f; unsigned int i; } x; x.f = f;
    unsigned int lsb = (x.i >> 16) & 1u;
    x.i += 0x7fffu + lsb;   // round-to-nearest-even
    return (ushort_t)(x.i >> 16);
}

__device__ __forceinline__ void load_lds16(const void* g, void* l) {
    __builtin_amdgcn_global_load_lds(
        (const __attribute__((address_space(1))) int*)g,
        (__attribute__((address_space(3))) int*)l, 16, 0, 0);
}

// ---------------------------------------------------------------------------
// Fused prep: ids < 4096 transpose one 32x32 tile of one W (wz = id>>10);
// ids >= 4096 grid-stride convert x f32 -> bf16.
// ---------------------------------------------------------------------------
__global__ __launch_bounds__(256) void prep_k(const float* __restrict__ X,
                                              ushort_t* __restrict__ Xb,
                                              const float* __restrict__ W0,
                                              const float* __restrict__ W1,
                                              const float* __restrict__ W2,
                                              const float* __restrict__ W3,
                                              ushort_t* __restrict__ WT0)
{
    __shared__ float tile[32][33];
    const int id = blockIdx.x;
    const int tid = threadIdx.x;
    if (id < 4096) {
        const float* Ws[4] = {W0, W1, W2, W3};
        const int wz = id >> 10, rem = id & 1023;
        const float* W = Ws[wz];
        ushort_t* WT = WT0 + (size_t)wz * DMODEL * DMODEL;
        int tx = tid & 31, ty = tid >> 5;
        int kb = (rem & 31) << 5, nb = (rem >> 5) << 5;
#pragma unroll
        for (int i = 0; i < 4; i++)
            tile[ty + i * 8][tx] = W[(size_t)(kb + ty + i * 8) * DMODEL + nb + tx];
        __syncthreads();
#pragma unroll
        for (int i = 0; i < 4; i++)
            WT[(size_t)(nb + ty + i * 8) * DMODEL + kb + tx] = f2bf(tile[tx][ty + i * 8]);
    } else {
        const int n4 = (int)((size_t)BATCH * SEQ * DMODEL / 4);
        int i = (id - 4096) * 256 + tid;
        const int stride = 2048 * 256;
        for (; i < n4; i += stride) {
            float4 v = ((const float4*)X)[i];
            ushort4 u;
            u.x = f2bf(v.x); u.y = f2bf(v.y); u.z = f2bf(v.z); u.w = f2bf(v.w);
            ((ushort4*)Xb)[i] = u;
        }
    }
}

// ---------------------------------------------------------------------------
// MFMA GEMM, 32x32x16, 4-slot ring + counted vmcnt + per-phase double barriers
// (r8 configuration verbatim — confirmed best of 7 variants: 144 us QKV).
// 256x256 tile, BK=32, 8 waves (2M x 4N), 2-D grid.
// MODE 0: fused QKV. N=3072; feature(elu+1) for n<2048; bf16 scatter [b,h,t,d].
// MODE 2: +bias, f32 row-major [M,N].
// ---------------------------------------------------------------------------
#define TBM 256
#define TBN 256
#define TBK 32

template<int MODE>
__global__ __launch_bounds__(512, 2) void mgemm32_k(const ushort_t* __restrict__ Ap,
                                                    const ushort_t* __restrict__ Bt,
                                                    const float* __restrict__ bias,
                                                    void* __restrict__ Cp,
                                                    int M, int N, int K)
{
    __shared__ short smem[65536];              // 4 x (A 8192 | B 8192) shorts
    const int tid = threadIdx.x;
    const int l  = tid & 63;
    const int w  = tid >> 6;
    const int wm = w >> 2, wn = w & 3;         // 2 x 4 wave grid
    const int l31 = l & 31;
    const int hi  = l >> 5;                    // 0/1 -> k-group

    const size_t m0 = (size_t)blockIdx.x * TBM;
    const size_t n0 = (size_t)blockIdx.y * TBN;

    f32x16 acc[4][2];
#pragma unroll
    for (int i = 0; i < 4; i++)
#pragma unroll
        for (int j = 0; j < 2; j++)
#pragma unroll
            for (int e = 0; e < 16; e++) acc[i][j][e] = 0.f;

    auto STAGE_PAIR = [&](int slot, int k0, int i) {
        short* Asl = smem + slot * 16384;
        short* Bsl = Asl + 8192;
        const int sa  = w * 2 + i;              // 0..15 segments of 1KB
        const int kch = sa >> 2;                // k-chunk 0..3
        const int rb  = sa & 3;                 // row-block of 64
        const int ldso = (kch * 256 + rb * 64) * 8;
        load_lds16(Ap + (m0 + rb * 64 + l) * (size_t)K + k0 + kch * 8, Asl + ldso);
        load_lds16(Bt + (n0 + rb * 64 + l) * (size_t)K + k0 + kch * 8, Bsl + ldso);
    };

    const int nt = K / TBK;                     // 32 for K=1024
    STAGE_PAIR(0, 0, 0);       STAGE_PAIR(0, 0, 1);
    STAGE_PAIR(1, TBK, 0);     STAGE_PAIR(1, TBK, 1);
    STAGE_PAIR(2, 2 * TBK, 0); STAGE_PAIR(2, 2 * TBK, 1);
    asm volatile("s_waitcnt vmcnt(8)" ::: "memory");   // tile0 landed; 1,2 in flight
    __builtin_amdgcn_sched_barrier(0);
    __builtin_amdgcn_s_barrier();

    for (int t = 0; t < nt; ++t) {
        const short* Asl = smem + (t & 3) * 16384;
        const short* Bsl = Asl + 8192;
        const bool pre = (t + 3 < nt);
        const int pslot = (t + 3) & 3;
        const int pk0 = (t + 3) * TBK;

        // ---------------- phase A (kk=0) ----------------
        if (pre) STAGE_PAIR(pslot, pk0, 0);
        short8 a0[4], b0[2];
#pragma unroll
        for (int mt = 0; mt < 4; mt++)
            a0[mt] = *(const short8*)(Asl + (hi * 256 + wm * 128 + mt * 32 + l31) * 8);
#pragma unroll
        for (int nn = 0; nn < 2; nn++)
            b0[nn] = *(const short8*)(Bsl + (hi * 256 + wn * 64 + nn * 32 + l31) * 8);
        __builtin_amdgcn_sched_barrier(0);
        __builtin_amdgcn_s_barrier();
        asm volatile("s_waitcnt lgkmcnt(0)" ::: "memory");
        __builtin_amdgcn_sched_barrier(0);
        __builtin_amdgcn_s_setprio(1);
#pragma unroll
        for (int mt = 0; mt < 4; mt++)
#pragma unroll
            for (int nn = 0; nn < 2; nn++)
                acc[mt][nn] = __builtin_amdgcn_mfma_f32_32x32x16_bf16(
                    a0[mt], b0[nn], acc[mt][nn], 0, 0, 0);
        __builtin_amdgcn_s_setprio(0);
        __builtin_amdgcn_s_barrier();

        // ---------------- phase B (kk=1) ----------------
        if (pre) STAGE_PAIR(pslot, pk0, 1);
        short8 a1[4], b1[2];
#pragma unroll
        for (int mt = 0; mt < 4; mt++)
            a1[mt] = *(const short8*)(Asl + ((2 + hi) * 256 + wm * 128 + mt * 32 + l31) * 8);
#pragma unroll
        for (int nn = 0; nn < 2; nn++)
            b1[nn] = *(const short8*)(Bsl + ((2 + hi) * 256 + wn * 64 + nn * 32 + l31) * 8);
        __builtin_amdgcn_sched_barrier(0);
        __builtin_amdgcn_s_barrier();
        asm volatile("s_waitcnt lgkmcnt(0)" ::: "memory");
        __builtin_amdgcn_sched_barrier(0);
        __builtin_amdgcn_s_setprio(1);
#pragma unroll
        for (int mt = 0; mt < 4; mt++)
#pragma unroll
            for (int nn = 0; nn < 2; nn++)
                acc[mt][nn] = __builtin_amdgcn_mfma_f32_32x32x16_bf16(
                    a1[mt], b1[nn], acc[mt][nn], 0, 0, 0);
        __builtin_amdgcn_s_setprio(0);

        // ---------------- tile boundary ----------------
        if (t + 3 < nt) {
            asm volatile("s_waitcnt vmcnt(8)" ::: "memory");   // t+1 landed
        } else if (t + 2 < nt) {
            asm volatile("s_waitcnt vmcnt(4)" ::: "memory");
        } else if (t + 1 < nt) {
            asm volatile("s_waitcnt vmcnt(0)" ::: "memory");
        }
        __builtin_amdgcn_sched_barrier(0);
        __builtin_amdgcn_s_barrier();
    }

    // epilogue: m = m0+wm*128+mt*32+row, n = n0+wn*64+nn*32+col
    // col = l&31, row = (reg&3) + 8*(reg>>2) + 4*(l>>5)
#pragma unroll
    for (int mt = 0; mt < 4; mt++) {
#pragma unroll
        for (int nn = 0; nn < 2; nn++) {
#pragma unroll
            for (int reg = 0; reg < 16; reg++) {
                int row = (reg & 3) + 8 * (reg >> 2) + 4 * hi;
                int m = (int)m0 + wm * 128 + mt * 32 + row;
                int n = (int)n0 + wn * 64 + nn * 32 + l31;
                float v = acc[mt][nn][reg];
                if (MODE == 2) {
                    ((float*)Cp)[(size_t)m * N + n] = v + bias[n];
                } else {
                    if (n < 2048) v = (v > 0.f) ? (v + 1.f) : __expf(v);  // Q,K feature
                    int tns = n >> 10, nnn = n & 1023;
                    int b_ = m >> 12, t_ = m & 4095, h_ = nnn >> 6, d_ = nnn & 63;
                    ushort_t* base = (ushort_t*)Cp + (size_t)tns * BATCH * SEQ * DMODEL;
                    base[((((size_t)b_ * NH + h_) * SEQ + t_) << 6) + d_] = f2bf(v);
                }
            }
        }
    }
}

// ---------------------------------------------------------------------------
// Fused z + kv dispatch. ids < 4096: Z for 4 (b,t) per block (one per wave).
// ids >= 4096: per-chunk S_local = K_c^T V_c via MFMA, bf16 out.
// ---------------------------------------------------------------------------
__global__ __launch_bounds__(256) void zkv_k(const ushort_t* __restrict__ Qf,
                                             const ushort_t* __restrict__ Kf,
                                             const ushort_t* __restrict__ Vf,
                                             float* __restrict__ Z,
                                             ushort_t* __restrict__ Sloc)
{
    __shared__ short KTs[8192];
    __shared__ short VTs[8192];
    const int id = blockIdx.x;
    const int tid = threadIdx.x;
    if (id < 4096) {
        // ---- Z part ----
        int bt = id * 4 + (tid >> 6);
        int b_ = bt >> 12, t_ = bt & 4095;
        int d = tid & 63;
        float qv[NH], kv[NH];
        size_t base = (((size_t)b_ * NH) * SEQ + t_) * DH + d;
#pragma unroll
        for (int h = 0; h < NH; h++) {
            qv[h] = bf2f(Qf[base + (size_t)h * SEQ * DH]);
            kv[h] = bf2f(Kf[base + (size_t)h * SEQ * DH]);
        }
        float ck = 0.f;
#pragma unroll
        for (int h = 0; h < NH; h++) {
            ck += kv[h];
            float p = qv[h] * ck;
#pragma unroll
            for (int off = 1; off < 64; off <<= 1) p += __shfl_xor(p, off, 64);
            if (d == 0) Z[((size_t)b_ * NH + h) * SEQ + t_] = 1.f / (p + FEPS);
        }
        return;
    }
    // ---- kv part ----
    const int blk = id - 4096;
    const int l = tid & 63, w = tid >> 6;
    const int lr = l & 15, hi = l >> 4;
    const size_t rowbase = ((size_t)(blk >> 5) * SEQ + (size_t)(blk & 31) * CHUNKSZ) * DH;
    const uint4* K16 = (const uint4*)(Kf + rowbase);
    const uint4* V16 = (const uint4*)(Vf + rowbase);
#pragma unroll
    for (int i = 0; i < 4; i++) {
        int idx = tid + i * 256;
        union { uint4 q; ushort_t us[8]; } kk, vv;
        kk.q = K16[idx]; vv.q = V16[idx];
        int j = idx >> 3, e0 = (idx & 7) << 3;
#pragma unroll
        for (int s = 0; s < 8; s++) {
            int off = ((j >> 3) * 64 + e0 + s) * 8 + (j & 7);
            KTs[off] = (short)kk.us[s];
            VTs[off] = (short)vv.us[s];
        }
    }
    __syncthreads();
    f32x4 acc[4];
#pragma unroll
    for (int nt = 0; nt < 4; nt++) acc[nt] = (f32x4){0.f, 0.f, 0.f, 0.f};
#pragma unroll
    for (int ks = 0; ks < 4; ks++) {
        short8 af = *(const short8*)(KTs + ((ks * 4 + hi) * 64 + w * 16 + lr) * 8);
        short8 bf[4];
#pragma unroll
        for (int nt = 0; nt < 4; nt++)
            bf[nt] = *(const short8*)(VTs + ((ks * 4 + hi) * 64 + nt * 16 + lr) * 8);
#pragma unroll
        for (int nt = 0; nt < 4; nt++)
            acc[nt] = __builtin_amdgcn_mfma_f32_16x16x32_bf16(af, bf[nt], acc[nt], 0, 0, 0);
    }
    ushort_t* outp = Sloc + (size_t)blk * DH * DH;
#pragma unroll
    for (int nt = 0; nt < 4; nt++)
#pragma unroll
        for (int jr = 0; jr < 4; jr++) {
            int d_ = w * 16 + hi * 4 + jr;
            int e_ = nt * 16 + lr;
            outp[d_ * DH + e_] = f2bf(acc[nt][jr]);
        }
}

// ---------------------------------------------------------------------------
// Exclusive prefix over chunks; load-all-then-store (one latency, not 32)
// ---------------------------------------------------------------------------
__global__ __launch_bounds__(256) void scan_k(ushort_t* __restrict__ Sloc)
{
    int bh = blockIdx.x, seg = blockIdx.y;
    int e = seg * 256 + threadIdx.x;
    ushort_t* base = Sloc + (size_t)bh * NCHUNK * DH * DH + e;
    float v[NCHUNK];
#pragma unroll
    for (int cc = 0; cc < NCHUNK; cc++) v[cc] = bf2f(base[(size_t)cc * DH * DH]);
    float acc = 0.f;
#pragma unroll
    for (int cc = 0; cc < NCHUNK; cc++) {
        float t = v[cc];
        base[(size_t)cc * DH * DH] = f2bf(acc);
        acc += t;
    }
}

// ---------------------------------------------------------------------------
// MFMA attention chunk kernel; S_pre bf16 (direct-copy staging)
// ---------------------------------------------------------------------------
__global__ __launch_bounds__(256) void attn_k(const ushort_t* __restrict__ Qf,
                                              const ushort_t* __restrict__ Kf,
                                              const ushort_t* __restrict__ Vf,
                                              const ushort_t* __restrict__ Sloc,
                                              const float* __restrict__ Z,
                                              ushort_t* __restrict__ A)
{
    __shared__ short smem[36864];
    short* Qs  = smem;
    short* Ks  = smem + 8192;
    short* Ps  = smem + 8192;
    short* VTs = smem + 24576;
    short* STs = smem + 32768;

    const int tid = threadIdx.x;
    const int l = tid & 63, w = tid >> 6;
    const int lr = l & 15, hi = l >> 4;
    const int blk = blockIdx.x;
    const int c = blk & (NCHUNK - 1), bh = blk >> 5;
    const int b_ = bh >> 4, h_ = bh & 15;
    const size_t rowbase = ((size_t)bh * SEQ + (size_t)c * CHUNKSZ) * DH;

#pragma unroll
    for (int ii = 0; ii < 4; ii++) {
        int s = w * 4 + ii;
        int kc2 = s >> 1, rh = (s & 1) << 6;
        int ldso = (kc2 * 128 + rh) * 8;
        load_lds16(Qf + rowbase + (size_t)(rh + l) * DH + kc2 * 8, Qs + ldso);
        load_lds16(Kf + rowbase + (size_t)(rh + l) * DH + kc2 * 8, Ks + ldso);
    }
    {
        const uint4* V16 = (const uint4*)(Vf + rowbase);
#pragma unroll
        for (int i = 0; i < 4; i++) {
            int idx = tid + i * 256;
            union { uint4 q; ushort_t us[8]; } vv;
            vv.q = V16[idx];
            int j = idx >> 3, e0 = (idx & 7) << 3;
#pragma unroll
            for (int s = 0; s < 8; s++)
                VTs[((j >> 3) * 64 + e0 + s) * 8 + (j & 7)] = (short)vv.us[s];
        }
    }
    {
        const uint4* S16 = (const uint4*)(Sloc + (size_t)blk * DH * DH);
#pragma unroll
        for (int i = 0; i < 2; i++) {
            int idx = tid + i * 256;              // 512 x 16B = 64x64 bf16
            union { uint4 q; ushort_t us[8]; } ss;
            ss.q = S16[idx];
            int d = idx >> 3, e0 = (idx & 7) << 3;
#pragma unroll
            for (int s = 0; s < 8; s++)
                STs[((d >> 3) * 64 + e0 + s) * 8 + (d & 7)] = (short)ss.us[s];
        }
    }
    __syncthreads();

    f32x4 acc1[2][8];
#pragma unroll
    for (int mt = 0; mt < 2; mt++)
#pragma unroll
        for (int nt = 0; nt < 8; nt++) acc1[mt][nt] = (f32x4){0.f, 0.f, 0.f, 0.f};
#pragma unroll
    for (int ks = 0; ks < 2; ks++) {
        short8 af[2], bf[8];
#pragma unroll
        for (int mt = 0; mt < 2; mt++)
            af[mt] = *(const short8*)(Qs + ((ks * 4 + hi) * 128 + w * 32 + mt * 16 + lr) * 8);
#pragma unroll
        for (int nt = 0; nt < 8; nt++)
            bf[nt] = *(const short8*)(Ks + ((ks * 4 + hi) * 128 + nt * 16 + lr) * 8);
#pragma unroll
        for (int mt = 0; mt < 2; mt++)
#pragma unroll
            for (int nt = 0; nt < 8; nt++)
                acc1[mt][nt] = __builtin_amdgcn_mfma_f32_16x16x32_bf16(
                    af[mt], bf[nt], acc1[mt][nt], 0, 0, 0);
    }
    __syncthreads();

#pragma unroll
    for (int mt = 0; mt < 2; mt++)
#pragma unroll
        for (int nt = 0; nt < 8; nt++)
#pragma unroll
            for (int jr = 0; jr < 4; jr++) {
                int i_ = w * 32 + mt * 16 + hi * 4 + jr;
                int j_ = nt * 16 + lr;
                float v = (j_ <= i_) ? acc1[mt][nt][jr] : 0.f;
                Ps[((j_ >> 3) * 128 + i_) * 8 + (j_ & 7)] = (short)f2bf(v);
            }
    __syncthreads();

    f32x4 acc2[2][4];
#pragma unroll
    for (int mt = 0; mt < 2; mt++)
#pragma unroll
        for (int nt = 0; nt < 4; nt++) acc2[mt][nt] = (f32x4){0.f, 0.f, 0.f, 0.f};
#pragma unroll
    for (int ks = 0; ks < 4; ks++) {
        short8 af[2], bf[4];
#pragma unroll
        for (int mt = 0; mt < 2; mt++)
            af[mt] = *(const short8*)(Ps + ((ks * 4 + hi) * 128 + w * 32 + mt * 16 + lr) * 8);
#pragma unroll
        for (int nt = 0; nt < 4; nt++)
            bf[nt] = *(const short8*)(VTs + ((ks * 4 + hi) * 64 + nt * 16 + lr) * 8);
#pragma unroll
        for (int mt = 0; mt < 2; mt++)
#pragma unroll
            for (int nt = 0; nt < 4; nt++)
                acc2[mt][nt] = __builtin_amdgcn_mfma_f32_16x16x32_bf16(
                    af[mt], bf[nt], acc2[mt][nt], 0, 0, 0);
    }
#pragma unroll
    for (int ks = 0; ks < 2; ks++) {
        short8 af[2], bf[4];
#pragma unroll
        for (int mt = 0; mt < 2; mt++)
            af[mt] = *(const short8*)(Qs + ((ks * 4 + hi) * 128 + w * 32 + mt * 16 + lr) * 8);
#pragma unroll
        for (int nt = 0; nt < 4; nt++)
            bf[nt] = *(const short8*)(STs + ((ks * 4 + hi) * 64 + nt * 16 + lr) * 8);
#pragma unroll
        for (int mt = 0; mt < 2; mt++)
#pragma unroll
            for (int nt = 0; nt < 4; nt++)
                acc2[mt][nt] = __builtin_amdgcn_mfma_f32_16x16x32_bf16(
                    af[mt], bf[nt], acc2[mt][nt], 0, 0, 0);
    }

#pragma unroll
    for (int mt = 0; mt < 2; mt++) {
#pragma unroll
        for (int jr = 0; jr < 4; jr++) {
            int i_ = w * 32 + mt * 16 + hi * 4 + jr;
            int t_ = c * CHUNKSZ + i_;
            float z = Z[(size_t)bh * SEQ + t_];
            ushort_t* op = A + (((size_t)(b_ * SEQ + t_)) * NH + h_) * DH;
#pragma unroll
            for (int nt = 0; nt < 4; nt++)
                op[nt * 16 + lr] = f2bf(acc2[mt][nt][jr] * z);
        }
    }
}

// ---------------------------------------------------------------------------
extern "C" void kernel_launch(void* const* d_in, const int* in_sizes, int n_in,
                              void* d_out, int out_size, void* d_ws, size_t ws_size,
                              hipStream_t stream)
{
    const float* x  = (const float*)d_in[0];
    const float* Wq = (const float*)d_in[1];
    const float* Wk = (const float*)d_in[2];
    const float* Wv = (const float*)d_in[3];
    const float* Wo = (const float*)d_in[4];
    const float* bo = (const float*)d_in[5];
    float* out = (float*)d_out;

    const size_t NEL = (size_t)BATCH * SEQ * DMODEL;
    const size_t WEL = (size_t)DMODEL * DMODEL;
    ushort_t* Qb  = (ushort_t*)d_ws;                   // Q,K,V contiguous (fused scatter)
    ushort_t* Kb  = Qb + NEL;
    ushort_t* Vb  = Kb + NEL;
    ushort_t* XAb = Vb + NEL;                          // x bf16, later attn out
    float*    Zb  = (float*)(XAb + NEL);
    ushort_t* WTq = (ushort_t*)(Zb + (size_t)BATCH * NH * SEQ);  // WTq|WTk|WTv|WTo contiguous
    ushort_t* WTo = WTq + 3 * WEL;
    ushort_t* Sl  = (ushort_t*)d_out;                  // bf16 scratch; final gemm overwrites

    const int M = BATCH * SEQ;

    // fused W-transpose (4096 blocks) + x->bf16 convert (2048 blocks)
    prep_k<<<dim3(6144), dim3(256), 0, stream>>>(x, XAb, Wq, Wk, Wv, Wo, WTq);

    // fused QKV: N = 3072 over concatenated [WTq|WTk|WTv]; 2-D grid (r8 locality)
    mgemm32_k<0><<<dim3(M / TBM, 3 * DMODEL / TBN), dim3(512), 0, stream>>>(
        XAb, WTq, nullptr, Qb, M, 3 * DMODEL, DMODEL);

    // fused Z (4096 blocks) + per-chunk K^T V (2048 blocks)
    zkv_k<<<dim3(6144), dim3(256), 0, stream>>>(Qb, Kb, Vb, Zb, Sl);

    scan_k<<<dim3(BATCH * NH, 16), dim3(256), 0, stream>>>(Sl);
    attn_k<<<dim3(BATCH * NH * NCHUNK), dim3(256), 0, stream>>>(Qb, Kb, Vb, Sl, Zb, XAb);

    mgemm32_k<2><<<dim3(M / TBM, DMODEL / TBN), dim3(512), 0, stream>>>(
        XAb, WTo, bo, out, M, DMODEL, DMODEL);
}